// Round 11
// baseline (381.257 us; speedup 1.0000x reference)
//
#include <hip/hip_runtime.h>
#include <hip/hip_bf16.h>
#include <math.h>
#include <type_traits>

#define AS1 __attribute__((address_space(1)))
#define AS3 __attribute__((address_space(3)))

typedef __bf16  bf16x8 __attribute__((ext_vector_type(8)));
typedef float   f32x4  __attribute__((ext_vector_type(4)));
typedef __hip_bfloat16 bf16;

#define MFMA16x16x32 __builtin_amdgcn_mfma_f32_16x16x32_bf16

__device__ __forceinline__ void gload16(const void* g, void* l) {
  // async global->LDS, 16B per lane; LDS dest = wave-uniform base + lane*16
  __builtin_amdgcn_global_load_lds((const AS1 void*)g, (AS3 void*)l, 16, 0, 0);
}

__device__ __forceinline__ unsigned short bfbits(float v) {
  return __builtin_bit_cast(unsigned short, __float2bfloat16(v));
}

// ---------------------------------------------------------------- fused fp32 -> bf16 casts
struct CastArgs {
  const float4* src[6];
  ushort4* dst[6];
  unsigned bound[6];  // cumulative float4 counts
};

__global__ __launch_bounds__(256) void f2bf_multi(CastArgs a) {
  unsigned i = blockIdx.x * 256 + threadIdx.x;
  if (i >= a.bound[5]) return;
  unsigned lo = 0;
  int s = 0;
#pragma unroll
  for (int k = 0; k < 5; k++) {
    if (i >= a.bound[k]) { s = k + 1; lo = a.bound[k]; }
  }
  unsigned idx = i - lo;
  float4 v = a.src[s][idx];
  ushort4 o;
  o.x = bfbits(v.x); o.y = bfbits(v.y); o.z = bfbits(v.z); o.w = bfbits(v.w);
  a.dst[s][idx] = o;
}

// ---------------------------------------------------------------- GEMM  C = A * W^T  (128x128, BK=64)
// R10-verified (369 us total): m97-style 2-barrier structure + BK=64
// (chunk^(row&7) LDS swizzle via pre-swizzled global sources) + T1 XCD
// swizzle (1-D grid, bijective for nwg%8==0).
template <typename OutT>
__global__ __launch_bounds__(256, 3) void gemm_bt64(const bf16* __restrict__ A,
                                                    const bf16* __restrict__ W,
                                                    OutT* __restrict__ Cp,
                                                    int N, int K, int lda) {
  __shared__ __align__(16) bf16 As[128 * 64];
  __shared__ __align__(16) bf16 Ws[128 * 64];
  const int t = threadIdx.x;
  const int w = t >> 6, lane = t & 63;
  const int quad = lane >> 4, l16 = lane & 15;
  const int wr = (w >> 1) * 64, wc = (w & 1) * 64;
  const unsigned bid = blockIdx.x, nwg = gridDim.x;
  const unsigned swz = (bid & 7) * (nwg >> 3) + (bid >> 3);
  const size_t m0 = (size_t)(swz & 31) * 128;
  const size_t n0 = (size_t)(swz >> 5) * 128;

  const int r8 = lane >> 3;
  const int cg = (lane & 7) ^ r8;
  const bf16* aSrc = A + (m0 + w * 8 + r8) * (size_t)lda + cg * 8;
  const bf16* wSrc = W + (n0 + w * 8 + r8) * (size_t)K + cg * 8;
  const size_t sA = (size_t)32 * lda, sW = (size_t)32 * K;

  const int cx0 = ((quad) ^ (l16 & 7)) << 4;
  const int cx1 = ((4 + quad) ^ (l16 & 7)) << 4;
  const char* aRb = (const char*)As + (wr + l16) * 128;
  const char* bRb = (const char*)Ws + (wc + l16) * 128;

  f32x4 acc[4][4];
#pragma unroll
  for (int i = 0; i < 4; i++)
#pragma unroll
    for (int j = 0; j < 4; j++) acc[i][j] = f32x4{0.f, 0.f, 0.f, 0.f};

  for (int k0 = 0; k0 < K; k0 += 64) {
    __syncthreads();
#pragma unroll
    for (int is = 0; is < 4; ++is)
      gload16(aSrc + is * sA, (char*)As + is * 4096 + w * 1024);
#pragma unroll
    for (int is = 0; is < 4; ++is)
      gload16(wSrc + is * sW, (char*)Ws + is * 4096 + w * 1024);
    aSrc += 64; wSrc += 64;
    __syncthreads();

    bf16x8 af[4][2], bw[4][2];
#pragma unroll
    for (int i = 0; i < 4; i++) {
      af[i][0] = *(const bf16x8*)(aRb + i * 2048 + cx0);
      af[i][1] = *(const bf16x8*)(aRb + i * 2048 + cx1);
    }
#pragma unroll
    for (int j = 0; j < 4; j++) {
      bw[j][0] = *(const bf16x8*)(bRb + j * 2048 + cx0);
      bw[j][1] = *(const bf16x8*)(bRb + j * 2048 + cx1);
    }
    __builtin_amdgcn_s_setprio(1);
#pragma unroll
    for (int i = 0; i < 4; i++)
#pragma unroll
      for (int j = 0; j < 4; j++)
#pragma unroll
        for (int ks = 0; ks < 2; ks++)
          acc[i][j] = MFMA16x16x32(af[i][ks], bw[j][ks], acc[i][j], 0, 0, 0);
    __builtin_amdgcn_s_setprio(0);
  }

#pragma unroll
  for (int i = 0; i < 4; i++)
#pragma unroll
    for (int j = 0; j < 4; j++)
#pragma unroll
      for (int r = 0; r < 4; r++) {
        size_t row = m0 + wr + i * 16 + quad * 4 + r;
        size_t col = n0 + wc + j * 16 + l16;
        float v = acc[i][j][r];
        if constexpr (std::is_same<OutT, float>::value)
          Cp[row * N + col] = v;
        else
          Cp[row * N + col] = __float2bfloat16(v);
      }
}

// ---------------------------------------------------------------- kv_up GEMM (BK=64) with V-transpose epilogue
__global__ __launch_bounds__(256, 3) void gemm_kvup64(const bf16* __restrict__ A,
                                                      const bf16* __restrict__ W,
                                                      bf16* __restrict__ kvraw,
                                                      bf16* __restrict__ vT) {
  __shared__ __align__(16) bf16 As[128 * 64];
  __shared__ __align__(16) bf16 Ws[128 * 64];
  const int t = threadIdx.x;
  const int w = t >> 6, lane = t & 63;
  const int quad = lane >> 4, l16 = lane & 15;
  const int wr = (w >> 1) * 64, wc = (w & 1) * 64;
  const int K = 512, lda = 2048;
  const unsigned bid = blockIdx.x, nwg = gridDim.x;  // nwg = 1024
  const unsigned swz = (bid & 7) * (nwg >> 3) + (bid >> 3);
  const size_t m0 = (size_t)(swz & 31) * 128;
  const int n0 = (int)(swz >> 5) * 128;

  const int r8 = lane >> 3;
  const int cg = (lane & 7) ^ r8;
  const bf16* aSrc = A + (m0 + w * 8 + r8) * (size_t)lda + cg * 8;
  const bf16* wSrc = W + ((size_t)n0 + w * 8 + r8) * (size_t)K + cg * 8;
  const size_t sA = (size_t)32 * lda, sW = (size_t)32 * K;

  const int cx0 = ((quad) ^ (l16 & 7)) << 4;
  const int cx1 = ((4 + quad) ^ (l16 & 7)) << 4;
  const char* aRb = (const char*)As + (wr + l16) * 128;
  const char* bRb = (const char*)Ws + (wc + l16) * 128;

  f32x4 acc[4][4];
#pragma unroll
  for (int i = 0; i < 4; i++)
#pragma unroll
    for (int j = 0; j < 4; j++) acc[i][j] = f32x4{0.f, 0.f, 0.f, 0.f};

  for (int k0 = 0; k0 < K; k0 += 64) {
    __syncthreads();
#pragma unroll
    for (int is = 0; is < 4; ++is)
      gload16(aSrc + is * sA, (char*)As + is * 4096 + w * 1024);
#pragma unroll
    for (int is = 0; is < 4; ++is)
      gload16(wSrc + is * sW, (char*)Ws + is * 4096 + w * 1024);
    aSrc += 64; wSrc += 64;
    __syncthreads();

    bf16x8 af[4][2], bw[4][2];
#pragma unroll
    for (int i = 0; i < 4; i++) {
      af[i][0] = *(const bf16x8*)(aRb + i * 2048 + cx0);
      af[i][1] = *(const bf16x8*)(aRb + i * 2048 + cx1);
    }
#pragma unroll
    for (int j = 0; j < 4; j++) {
      bw[j][0] = *(const bf16x8*)(bRb + j * 2048 + cx0);
      bw[j][1] = *(const bf16x8*)(bRb + j * 2048 + cx1);
    }
    __builtin_amdgcn_s_setprio(1);
#pragma unroll
    for (int i = 0; i < 4; i++)
#pragma unroll
      for (int j = 0; j < 4; j++)
#pragma unroll
        for (int ks = 0; ks < 2; ks++)
          acc[i][j] = MFMA16x16x32(af[i][ks], bw[j][ks], acc[i][j], 0, 0, 0);
    __builtin_amdgcn_s_setprio(0);
  }

  if ((n0 & 128) == 0) {
    // K-half of a head: normal row-major store into kvraw
#pragma unroll
    for (int i = 0; i < 4; i++)
#pragma unroll
      for (int j = 0; j < 4; j++)
#pragma unroll
        for (int r = 0; r < 4; r++) {
          size_t row = m0 + wr + i * 16 + quad * 4 + r;
          size_t col = (size_t)n0 + wc + j * 16 + l16;
          kvraw[row * 4096 + col] = __float2bfloat16(acc[i][j][r]);
        }
  } else {
    // V-half: write transposed into vT[(b*16+h)*128 + d][t], 4 t-contiguous per store
    const int h = n0 >> 8;
#pragma unroll
    for (int i = 0; i < 4; i++) {
      size_t row = m0 + wr + i * 16 + quad * 4;  // +r, all same b
      int bb = (int)(row >> 11), tloc = (int)(row & 2047);
#pragma unroll
      for (int j = 0; j < 4; j++) {
        int d = wc + j * 16 + l16;  // in-head V index, 0..127
        ushort4 v4;
        v4.x = bfbits(acc[i][j][0]);
        v4.y = bfbits(acc[i][j][1]);
        v4.z = bfbits(acc[i][j][2]);
        v4.w = bfbits(acc[i][j][3]);
        *(ushort4*)(vT + ((size_t)(bb * 16 + h) * 128 + d) * 2048 + tloc) = v4;
      }
    }
  }
}

// ---------------------------------------------------------------- RoPE + RMSNorm
__global__ __launch_bounds__(256) void rope_rms(const bf16* __restrict__ qraw,
                                                const bf16* __restrict__ kvraw,
                                                const float* __restrict__ cosp,
                                                const float* __restrict__ sinp,
                                                bf16* __restrict__ qn,
                                                bf16* __restrict__ kn) {
  const int bt = blockIdx.x;
  const int w = threadIdx.x >> 6, lane = threadIdx.x & 63;
  const int h = blockIdx.y * 4 + w;
  const int tt = bt & 2047;  // T = 2048
  const float c = cosp[tt * 32 + (lane & 31)];
  const float s = sinp[tt * 32 + (lane & 31)];
  const float inv128 = 1.0f / 128.0f;
  const float eps = 1.1920929e-7f;

  // Q
  {
    const bf16* base = qraw + (size_t)bt * 2048 + h * 128;
    float a = (float)base[lane];
    float o = (float)base[64 + lane];
    float partner = __shfl_xor(o, 32);
    float orope = (lane < 32) ? (o * c + partner * s) : (o * c - partner * s);
    float ss = a * a + orope * orope;
#pragma unroll
    for (int off = 1; off < 64; off <<= 1) ss += __shfl_xor(ss, off);
    float rn = rsqrtf(ss * inv128 + eps);
    bf16* outp = qn + ((size_t)bt * 16 + h) * 128;
    outp[lane] = __float2bfloat16(a * rn);
    outp[64 + lane] = __float2bfloat16(orope * rn);
  }
  // K
  {
    const bf16* base = kvraw + (size_t)bt * 4096 + h * 256;
    float a = (float)base[lane];
    float o = (float)base[64 + lane];
    float partner = __shfl_xor(o, 32);
    float orope = (lane < 32) ? (o * c + partner * s) : (o * c - partner * s);
    float ss = a * a + orope * orope;
#pragma unroll
    for (int off = 1; off < 64; off <<= 1) ss += __shfl_xor(ss, off);
    float rn = rsqrtf(ss * inv128 + eps);
    bf16* outp = kn + ((size_t)bt * 16 + h) * 128;
    outp[lane] = __float2bfloat16(a * rn);
    outp[64 + lane] = __float2bfloat16(orope * rn);
  }
}

// ---------------------------------------------------------------- flash attention
// R11: KVBLK=32 + double-buffer + 4 blocks/CU — combines R1's TLP (4 blk/CU,
// exact-balance bijection, 66 tile64-equivalents/CU) with R2's pipeline
// (prefetch + counted vmcnt(4)).  LDS 36 KB: Ks 2x[32][128] + Vs 2x[128][32]
// + Ps [4][16][32].  Work per s-element unchanged; nt32=2(xb+1) always even
// (clean x2 unroll, no tail).  Causal mask spans the last TWO half-tiles
// (soff in {0,32}).  Swizzles re-derived: K ^(srow&7) (unchanged), V chunks 4
// -> ^(d&3), Ps [16][32] chunk ^(row&3).
__global__ __launch_bounds__(256, 4) void attn_kernel(const bf16* __restrict__ qn,
                                                      const bf16* __restrict__ kn,
                                                      const bf16* __restrict__ vT,
                                                      bf16* __restrict__ y) {
  __shared__ __align__(16) bf16 Ks[2 * 32 * 128];   // 16 KB  [buf][s][d-chunks swz]
  __shared__ __align__(16) bf16 Vs[2 * 128 * 32];   // 16 KB  [buf][d][s-chunks swz]
  __shared__ __align__(16) bf16 Ps[4 * 16 * 32];    //  4 KB  per-wave P, swz
  const int t = threadIdx.x, w = t >> 6, lane = t & 63;
  const int quad = lane >> 4, l16 = lane & 15;
  const int b = blockIdx.x >> 4, h = blockIdx.x & 15;
  const int yy = (int)blockIdx.y;
  const int y0 = yy & 7, k4 = yy >> 3;
  int xb;
  if (k4 == 0) xb = 31 - y0;
  else if (k4 == 1) xb = y0;
  else if (k4 == 2) xb = 23 - y0;
  else xb = 8 + y0;
  const int q0 = xb * 64;
  const int nt = 2 * xb + 2;   // 32-wide tiles; always even
  const int it2x = 2 * xb;     // first diagonal half-tile
  const int T_ = 2048, H_ = 16;
  const float K1 = 0.08838834764831845f * 1.4426950408889634f;
  const float K2 = -12.0f * 1.4426950408889634f;

  // K staging: sweep is in {0,1}: row = is*16 + w*4 + quad, chunk l16^((w*4+quad)&7)
  const int cgk = l16 ^ ((w * 4 + quad) & 7);
  const char* kg0 = (const char*)(kn + ((size_t)(b * T_) * H_ + h) * 128)
                    + (size_t)(w * 4 + quad) * 4096 + (size_t)cgk * 16;
  // V staging: sweep is: row d = is*64 + w*16 + (lane>>2), chunk (lane&3)^((lane>>2)&3)
  const int vrow = w * 16 + (lane >> 2);
  const int cgv = (lane & 3) ^ ((lane >> 2) & 3);
  const char* vg0 = (const char*)(vT + ((size_t)(b * H_ + h) * 128 + vrow) * T_)
                    + (size_t)cgv * 16;

  // stage K/V half-tile it2 (4 gload16/thread) into buffer BUF
  auto stage = [&](auto bufc, int it2) {
    constexpr int BUF = decltype(bufc)::value;
    const size_t koff = (size_t)it2 * 131072;  // 32 rows * 4096 B
    const size_t voff = (size_t)it2 * 64;      // 32 cols * 2 B
#pragma unroll
    for (int is = 0; is < 2; ++is)
      gload16(kg0 + koff + (size_t)is * 65536,
              (char*)Ks + BUF * 8192 + is * 4096 + w * 1024);
#pragma unroll
    for (int is = 0; is < 2; ++is)
      gload16(vg0 + voff + (size_t)is * 262144,
              (char*)Vs + BUF * 8192 + is * 4096 + w * 1024);
  };

  auto body = [&](auto bufc, int it, bf16x8* qf, f32x4* yacc, float* lrow) {
    constexpr int BUF = decltype(bufc)::value;
    if (it + 1 < nt) {
      stage(std::integral_constant<int, 1 - BUF>{}, it + 1);
      __asm__ volatile("s_waitcnt vmcnt(4)" ::: "memory");  // tile-it loads done
    } else {
      __asm__ volatile("s_waitcnt vmcnt(0)" ::: "memory");
    }
    __asm__ volatile("s_barrier" ::: "memory");

    // S = Q K^T  (2 cg x 4 ks = 8 MFMA)
    f32x4 sacc[2];
#pragma unroll
    for (int cg = 0; cg < 2; cg++) sacc[cg] = f32x4{0.f, 0.f, 0.f, 0.f};
    __builtin_amdgcn_s_setprio(1);
#pragma unroll
    for (int cg = 0; cg < 2; ++cg) {
#pragma unroll
      for (int ks = 0; ks < 4; ++ks) {
        const int pos = (ks * 4 + quad) ^ (l16 & 7);  // srow&7 == l16&7
        const bf16x8 kf = *(const bf16x8*)((const char*)Ks + BUF * 8192 +
                                           (cg * 16 + l16) * 256 + pos * 16);
        sacc[cg] = MFMA16x16x32(qf[ks], kf, sacc[cg], 0, 0, 0);
      }
    }
    __builtin_amdgcn_s_setprio(0);

    // fixed-max softmax; causal mask on the two diagonal half-tiles
    const bool diag = (it >= it2x);
    const int soff = (it - it2x) * 32;
    float p[2][4];
#pragma unroll
    for (int cg = 0; cg < 2; ++cg)
#pragma unroll
      for (int r = 0; r < 4; ++r) {
        float e;
        if (diag && (soff + cg * 16 + l16 > w * 16 + quad * 4 + r))
          e = 0.0f;
        else
          e = exp2f(fmaf(sacc[cg][r], K1, K2));
        p[cg][r] = e;
        lrow[r] += e;
      }

    // P: C-layout -> LDS [16][32] (chunk^(row&3) swizzle) -> A-layout
#pragma unroll
    for (int cg = 0; cg < 2; cg++)
#pragma unroll
      for (int r = 0; r < 4; r++) {
        const int row = quad * 4 + r;
        const int col = cg * 16 + l16;
        Ps[w * 512 + row * 32 + (((col >> 3) ^ (row & 3)) << 3) + (col & 7)] =
            __float2bfloat16(p[cg][r]);
      }
    __asm__ volatile("s_waitcnt lgkmcnt(0)" ::: "memory");

    const bf16x8 pf = *(const bf16x8*)(&Ps[w * 512 + l16 * 32 +
                                           ((quad ^ (l16 & 3)) << 3)]);
    __builtin_amdgcn_s_setprio(1);
#pragma unroll
    for (int dg = 0; dg < 8; dg++) {
      const int pos = quad ^ (l16 & 3);  // drow&3 == l16&3
      const bf16x8 vf = *(const bf16x8*)((const char*)Vs + BUF * 8192 +
                                         (dg * 16 + l16) * 64 + pos * 16);
      yacc[dg] = MFMA16x16x32(pf, vf, yacc[dg], 0, 0, 0);
    }
    __builtin_amdgcn_s_setprio(0);
    __asm__ volatile("s_barrier" ::: "memory");  // 1-BUF free to overwrite
  };

  const std::integral_constant<int, 0> c0{};
  const std::integral_constant<int, 1> c1{};

  bf16x8 qf[4];
  {
    const bf16* qbase = qn + ((size_t)(b * T_ + q0 + w * 16 + l16) * H_ + h) * 128;
#pragma unroll
    for (int ks = 0; ks < 4; ks++) qf[ks] = *(const bf16x8*)(qbase + ks * 32 + quad * 8);
  }
  f32x4 yacc[8];
#pragma unroll
  for (int i = 0; i < 8; i++) yacc[i] = f32x4{0.f, 0.f, 0.f, 0.f};
  float lrow[4] = {0.f, 0.f, 0.f, 0.f};

  stage(c0, 0);  // prologue prefetch into buf0
  for (int it = 0; it < nt; it += 2) {  // nt even: no tail
    body(c0, it, qf, yacc, lrow);
    body(c1, it + 1, qf, yacc, lrow);
  }

  // epilogue: reduce per-lane l partials across the 16 cols once, then scale
#pragma unroll
  for (int off = 1; off < 16; off <<= 1)
#pragma unroll
    for (int r = 0; r < 4; r++) lrow[r] += __shfl_xor(lrow[r], off);
#pragma unroll
  for (int r = 0; r < 4; r++) {
    float inv = 1.0f / lrow[r];
    size_t qrow = (size_t)(b * T_ + q0 + w * 16 + quad * 4 + r);
    bf16* outp = y + qrow * 2048 + h * 128;
#pragma unroll
    for (int dg = 0; dg < 8; dg++)
      outp[dg * 16 + l16] = __float2bfloat16(yacc[dg][r] * inv);
  }
}

// ---------------------------------------------------------------- launcher
extern "C" void kernel_launch(void* const* d_in, const int* in_sizes, int n_in,
                              void* d_out, int out_size, void* d_ws, size_t ws_size,
                              hipStream_t stream) {
  (void)in_sizes; (void)n_in; (void)out_size; (void)ws_size;
  const float* x    = (const float*)d_in[0];
  const float* cosp = (const float*)d_in[1];
  const float* sinp = (const float*)d_in[2];
  const float* wqd  = (const float*)d_in[3];
  const float* wqu  = (const float*)d_in[4];
  const float* wkvd = (const float*)d_in[5];
  const float* wkvu = (const float*)d_in[6];
  const float* wo   = (const float*)d_in[7];
  float* out = (float*)d_out;

  char* ws = (char*)d_ws;
  size_t off = 0;
  auto alloc = [&](size_t elems) { bf16* p = (bf16*)(ws + off); off += elems * 2; return p; };
  bf16* xb      = alloc((size_t)4096 * 2048);
  bf16* wqdB    = alloc((size_t)1536 * 2048);  // wqdB+wkvdB contiguous: fused (2048,2048) W
  bf16* wkvdB   = alloc((size_t)512 * 2048);
  bf16* wquB    = alloc((size_t)2048 * 1536);
  bf16* wkvuB   = alloc((size_t)4096 * 512);
  bf16* woB     = alloc((size_t)2048 * 2048);
  bf16* qkvdown = alloc((size_t)4096 * 2048);  // cols 0..1535 = qdown, 1536..2047 = kvdown
  bf16* qraw    = alloc((size_t)4096 * 2048);
  bf16* kvraw   = alloc((size_t)4096 * 4096);  // only K-halves written/used
  bf16* qnb     = alloc((size_t)4096 * 16 * 128);
  bf16* knb     = alloc((size_t)4096 * 16 * 128);
  bf16* vTb     = alloc((size_t)2 * 16 * 128 * 2048);
  bf16* yb      = alloc((size_t)4096 * 2048);

  // one fused cast launch for all six fp32->bf16 conversions
  CastArgs ca;
  const float* srcs[6] = {x, wqd, wkvd, wqu, wkvu, wo};
  bf16* dsts[6]        = {xb, wqdB, wkvdB, wquB, wkvuB, woB};
  size_t cnts[6] = {(size_t)4096 * 2048, (size_t)1536 * 2048, (size_t)512 * 2048,
                    (size_t)2048 * 1536, (size_t)4096 * 512,  (size_t)2048 * 2048};
  unsigned cum = 0;
  for (int i = 0; i < 6; i++) {
    ca.src[i] = (const float4*)srcs[i];
    ca.dst[i] = (ushort4*)dsts[i];
    cum += (unsigned)(cnts[i] / 4);
    ca.bound[i] = cum;
  }
  f2bf_multi<<<dim3((cum + 255) / 256), 256, 0, stream>>>(ca);

  // fused down-proj: (4096 x 2048) = x @ [wq_down; wkv_down]^T
  gemm_bt64<bf16><<<dim3(512), 256, 0, stream>>>(xb, wqdB, qkvdown, 2048, 2048, 2048);
  // q up-projection (strided A)
  gemm_bt64<bf16><<<dim3(512), 256, 0, stream>>>(qkvdown, wquB, qraw, 2048, 1536, 2048);
  // kv up-projection with fused V-transpose epilogue
  gemm_kvup64<<<dim3(1024), 256, 0, stream>>>(qkvdown + 1536, wkvuB, kvraw, vTb);
  rope_rms<<<dim3(4096, 4), 256, 0, stream>>>(qraw, kvraw, cosp, sinp, qnb, knb);
  attn_kernel<<<dim3(32, 32), 256, 0, stream>>>(qnb, knb, vTb, yb);
  gemm_bt64<float><<<dim3(512), 256, 0, stream>>>(yb, woB, out, 2048, 2048, 2048);
}